// Round 5
// baseline (127.096 us; speedup 1.0000x reference)
//
#include <hip/hip_runtime.h>

// IGD metric kernel for MI355X (gfx950) — R5: fp8 e4m3 + LDS-resident B split.
// d2(i,j) = pfsq[i] + xsq[j] + dot(e4m3(-2*pf_i), e4m3(x_j)); norms computed in fp32 from the
// DECODED fp8 values -> d2 is the exact squared distance between the rounded points (plus exact
// xsq/pfsq), so only the point-rounding perturbation (~0.02 per distance) reaches the output.
// Main kernel: NSPLIT=64 -> each block's B slice = 8 units x 2048 B = 16 KB fp8, staged into LDS
// ONCE (one barrier), then a barrier-free K-loop: per 32-col unit 8x v_mfma_f32_32x32x16_fp8_fp8
// + 64 VALU (add xsq, min). R4 post-mortem: per-wave B delivery through VMEM (~12 TB/s achieved)
// was the bottleneck; fp8 halves bytes and LDS (~70 TB/s) carries the stream instead.
// Harness poison fill of ws (~42 us) is a fixed floor inside the timed window.

typedef float f32x16 __attribute__((ext_vector_type(16)));
typedef unsigned long long u64;

#define DIM 64
#define NSPLIT 64
#define UNITS 8          // 32-col units per split (512 units total / 64 splits)
#define USTRIDE 2048     // bytes per unit in Bp: 4 K-frags x 64 lanes x 8 B
#define MTILE 256        // rows per block (4 waves x 64 rows)

// ---- manual OCP e4m3fn encode (RNE, denormals, saturate) / decode ----
__device__ inline unsigned char enc_e4m3(float f) {
    unsigned int u = __float_as_uint(f);
    unsigned int s = (u >> 24) & 0x80u;
    unsigned int a = u & 0x7FFFFFFFu;
    if ((a >> 23) >= 121u) {                       // |f| >= 2^-6 : normal range
        unsigned int lsb = (a >> 20) & 1u;
        unsigned int r = a + 0x7FFFFu + lsb;       // RNE on 3-bit mantissa
        int e = (int)(r >> 23) - 120;              // rebias 127 -> 7
        unsigned int m = (r >> 20) & 7u;
        if (e > 15 || (e == 15 && m == 7u)) return (unsigned char)(s | 0x7Eu);  // sat 448
        return (unsigned char)(s | ((unsigned)e << 3) | m);
    }
    int m = (int)rintf(__uint_as_float(a) * 512.0f);   // denormal: multiples of 2^-9 (m<=8 ok)
    return (unsigned char)(s | (unsigned)m);
}

__device__ inline float dec_e4m3(unsigned char b) {
    int e = (b >> 3) & 15, m = b & 7;
    float v = (e == 0) ? (float)m * 0.001953125f       // 2^-9
                       : (float)(8 + m) * exp2f((float)(e - 10));
    return (b & 0x80) ? -v : v;
}

// ---------------- pack ----------------
// x -> Bp fragment-linear fp8: unit u = col>>5, frag t (16 k), half h: byte j at
//   Bp[u*2048 + t*512 + (h*32 + (col&31))*8 + j] = e4m3(x[col][t*16 + h*8 + j])
// xsq[col] = exact fp32 sum of squares of decoded values.
// pf -> Ab row-major fp8(-2*pf); pfsq = 0.25 * sum(dec^2).
__global__ void pack_kernel(const float* __restrict__ x, const float* __restrict__ pf,
                            unsigned char* __restrict__ Bp, unsigned char* __restrict__ Ab,
                            float* __restrict__ xsq, float* __restrict__ pfsq,
                            float* __restrict__ out, int N, int M) {
    int gid = blockIdx.x * blockDim.x + threadIdx.x;
    if (gid == 0) out[0] = 0.f;
    if (gid < N * 4) {
        int col = gid >> 2, t = gid & 3;
        const float* s = x + (size_t)col * DIM + t * 16;
        float partial = 0.f;
        u64 w[2] = {0, 0};
#pragma unroll
        for (int h = 0; h < 2; ++h) {
            float4 v0 = *(const float4*)(s + h * 8);
            float4 v1 = *(const float4*)(s + h * 8 + 4);
            float f[8] = {v0.x, v0.y, v0.z, v0.w, v1.x, v1.y, v1.z, v1.w};
#pragma unroll
            for (int j = 0; j < 8; ++j) {
                unsigned char b = enc_e4m3(f[j]);
                w[h] |= (u64)b << (8 * j);
                float d = dec_e4m3(b);
                partial += d * d;
            }
        }
        int u = col >> 5, c31 = col & 31;
        unsigned char* ub = Bp + (size_t)u * USTRIDE + (size_t)t * 512;
        *(u64*)(ub + (size_t)c31 * 8)        = w[0];
        *(u64*)(ub + (size_t)(32 + c31) * 8) = w[1];
        partial += __shfl_xor(partial, 1);
        partial += __shfl_xor(partial, 2);
        if (t == 0) xsq[col] = partial;
    } else {
        int g = gid - N * 4;
        int row = g >> 2, q = g & 3;
        if (row >= M) return;
        const float* s = pf + (size_t)row * DIM + q * 16;
        float partial = 0.f;
        u64 w[2] = {0, 0};
#pragma unroll
        for (int h = 0; h < 2; ++h) {
            float4 v0 = *(const float4*)(s + h * 8);
            float4 v1 = *(const float4*)(s + h * 8 + 4);
            float f[8] = {v0.x, v0.y, v0.z, v0.w, v1.x, v1.y, v1.z, v1.w};
#pragma unroll
            for (int j = 0; j < 8; ++j) {
                unsigned char b = enc_e4m3(f[j] * -2.f);
                w[h] |= (u64)b << (8 * j);
                float d = dec_e4m3(b);
                partial += d * d;
            }
        }
        *(u64*)(Ab + (size_t)row * DIM + q * 16)     = w[0];
        *(u64*)(Ab + (size_t)row * DIM + q * 16 + 8) = w[1];
        partial += __shfl_xor(partial, 1);
        partial += __shfl_xor(partial, 2);
        if (q == 0) pfsq[row] = partial * 0.25f;
    }
}

// ---------------- main: LDS-resident B split, fused GEMM + row-min ----------------
__global__ __launch_bounds__(256, 3)
void igd_main(const unsigned char* __restrict__ A, const unsigned char* __restrict__ Bp,
              const float* __restrict__ xsq, float* __restrict__ partial) {
    __shared__ unsigned char ldsB[UNITS * USTRIDE];   // 16 KB
    __shared__ float ldsX[UNITS * 32];                // 1 KB
    const int tid = threadIdx.x;
    const int mTile  = blockIdx.x;
    const int nsplit = blockIdx.y;
    const int lane = tid & 63;
    const int wave = tid >> 6;
    const int half = lane >> 5;
    const int l31  = lane & 31;
    const int rowBase = mTile * MTILE + wave * 64;

    // Persistent A fragments (fp8): lane holds A[row=l31+32g][k=half*8+j] per 16-k frag
    u64 a[2][4];
#pragma unroll
    for (int g = 0; g < 2; ++g) {
        const unsigned char* ap = A + (size_t)(rowBase + 32 * g + l31) * DIM + half * 8;
#pragma unroll
        for (int kf = 0; kf < 4; ++kf)
            a[g][kf] = *(const u64*)(ap + kf * 16);
    }

    // Stage this split's whole B slice + xsq into LDS (one barrier, none in K-loop)
    {
        const char* gsrc = (const char*)Bp + (size_t)nsplit * (UNITS * USTRIDE);
#pragma unroll
        for (int i = 0; i < 4; ++i)
            *(float4*)(ldsB + i * 4096 + tid * 16) = *(const float4*)(gsrc + i * 4096 + tid * 16);
        ldsX[tid] = xsq[nsplit * (UNITS * 32) + tid];
    }
    __syncthreads();

    f32x16 zero, m0, m1;
#pragma unroll
    for (int r = 0; r < 16; ++r) { zero[r] = 0.f; m0[r] = 1e30f; m1[r] = 1e30f; }

    u64 b0[4], b1[4];
    float xqA, xqB;

#define LOADU(breg, xq, u)                                                     \
    {                                                                          \
        const unsigned char* p = ldsB + (u) * USTRIDE + lane * 8;              \
        breg[0] = *(const u64*)(p);                                            \
        breg[1] = *(const u64*)(p + 512);                                      \
        breg[2] = *(const u64*)(p + 1024);                                     \
        breg[3] = *(const u64*)(p + 1536);                                     \
        xq = ldsX[(u) * 32 + l31];                                             \
    }

#define COMPUTE(breg, xq)                                                      \
    {                                                                          \
        f32x16 acc0 = __builtin_amdgcn_mfma_f32_32x32x16_fp8_fp8((long)breg[0], (long)breg[0], zero, 0, 0, 0); \
        acc0 = zero;                                                           \
        acc0 = __builtin_amdgcn_mfma_f32_32x32x16_fp8_fp8((long)a[0][0], (long)breg[0], zero, 0, 0, 0); \
        f32x16 acc1 = __builtin_amdgcn_mfma_f32_32x32x16_fp8_fp8((long)a[1][0], (long)breg[0], zero, 0, 0, 0); \
        _Pragma("unroll")                                                      \
        for (int kf = 1; kf < 4; ++kf) {                                       \
            acc0 = __builtin_amdgcn_mfma_f32_32x32x16_fp8_fp8((long)a[0][kf], (long)breg[kf], acc0, 0, 0, 0); \
            acc1 = __builtin_amdgcn_mfma_f32_32x32x16_fp8_fp8((long)a[1][kf], (long)breg[kf], acc1, 0, 0, 0); \
        }                                                                      \
        _Pragma("unroll")                                                      \
        for (int r = 0; r < 16; ++r) {                                         \
            m0[r] = fminf(m0[r], acc0[r] + xq);                                \
            m1[r] = fminf(m1[r], acc1[r] + xq);                                \
        }                                                                      \
    }

    LOADU(b0, xqA, 0);
#pragma unroll
    for (int u = 0; u < UNITS; u += 2) {
        LOADU(b1, xqB, u + 1);
        COMPUTE(b0, xqA);
        if (u + 2 < UNITS) LOADU(b0, xqA, u + 2);
        COMPUTE(b1, xqB);
    }
#undef LOADU
#undef COMPUTE

    // cross-lane min over the 32 lanes sharing a row
#pragma unroll
    for (int mask = 1; mask <= 16; mask <<= 1) {
#pragma unroll
        for (int r = 0; r < 16; ++r) {
            m0[r] = fminf(m0[r], __shfl_xor(m0[r], mask));
            m1[r] = fminf(m1[r], __shfl_xor(m1[r], mask));
        }
    }
    if (l31 == 0) {
        // C/D layout (shape-determined, dtype-independent): row = (r&3) + 8*(r>>2) + 4*half
#pragma unroll
        for (int r = 0; r < 16; ++r) {
            int row0 = rowBase + (r & 3) + 8 * (r >> 2) + 4 * half;
            partial[(size_t)row0 * NSPLIT + nsplit] = m0[r];
            partial[(size_t)(row0 + 32) * NSPLIT + nsplit] = m1[r];
        }
    }
}

// ---------------- reduce: min over splits, add pfsq, sqrt, mean ----------------
__global__ void reduce_kernel(const float* __restrict__ partial, const float* __restrict__ pfsq,
                              float* __restrict__ out, int M, float invM) {
    int row = blockIdx.x * blockDim.x + threadIdx.x;
    float v = 0.f;
    if (row < M) {
        const float* p = partial + (size_t)row * NSPLIT;
        float mn = 3.4e38f;
#pragma unroll 8
        for (int s = 0; s < NSPLIT; ++s) mn = fminf(mn, p[s]);
        float d2 = mn + pfsq[row];
        v = sqrtf(fmaxf(d2, 0.f)) * invM;
    }
#pragma unroll
    for (int m = 1; m < 64; m <<= 1) v += __shfl_xor(v, m);
    __shared__ float wsum[4];
    int lane = threadIdx.x & 63, w = threadIdx.x >> 6;
    if (lane == 0) wsum[w] = v;
    __syncthreads();
    if (threadIdx.x == 0) atomicAdd(out, wsum[0] + wsum[1] + wsum[2] + wsum[3]);
}

extern "C" void kernel_launch(void* const* d_in, const int* in_sizes, int n_in,
                              void* d_out, int out_size, void* d_ws, size_t ws_size,
                              hipStream_t stream) {
    const float* x  = (const float*)d_in[0];   // [N, 64]
    const float* pf = (const float*)d_in[1];   // [M, 64]
    const int N = in_sizes[0] / DIM;
    const int M = in_sizes[1] / DIM;

    char* ws = (char*)d_ws;
    unsigned char* Bp = (unsigned char*)ws;                        // N*64 bytes (packed fp8)
    unsigned char* Ab = (unsigned char*)(ws + (size_t)N * DIM);    // M*64 bytes
    float* xsq  = (float*)(ws + (size_t)(N + M) * DIM);            // N floats
    float* pfsq = xsq + N;                                         // M floats
    float* part = pfsq + M;                                        // M*NSPLIT floats

    int packThreads = (N + M) * 4;
    pack_kernel<<<dim3((packThreads + 255) / 256), 256, 0, stream>>>(
        x, pf, Bp, Ab, xsq, pfsq, (float*)d_out, N, M);
    igd_main<<<dim3(M / MTILE, NSPLIT), 256, 0, stream>>>(Ab, Bp, xsq, part);
    reduce_kernel<<<dim3((M + 255) / 256), 256, 0, stream>>>(part, pfsq, (float*)d_out, M, 1.f / (float)M);
}

// Round 6
// 98.475 us; speedup vs baseline: 1.2906x; 1.2906x over previous
//
#include <hip/hip_runtime.h>

// IGD metric kernel for MI355X (gfx950) — R6: fp8 e4m3 + R3 streaming structure + depth-4 prefetch.
// d2(i,j) = pfsq[i] + xsq[j] + dot(e4m3(-2*pf_i), e4m3(x_j)); norms in fp32 from DECODED fp8 ->
// d2 = exact sq-distance between rounded points; only point-rounding (~0.02/dist) reaches output.
// R5 post-mortem: 8-unit blocks were prologue/barrier-dominated (block lifetime ~29k cyc for ~2k
// cyc MFMA). R6: NSPLIT=12 -> 768 blocks = exactly 3/CU, zero barriers, 42/43-unit K-loop;
// B lane-major (2x dwordx4 per 32-col unit instead of 4x dwordx2); 4-deep ping-pong vs R3's 2
// (R3 delivery 13.4 TB/s ~= depth-1 latency bound; need 19.4 TB/s at the 13.8us MFMA floor).
// Harness poison fill of ws (~42 us @6.4TB/s) is a fixed floor inside the timed window.

typedef float f32x16 __attribute__((ext_vector_type(16)));
typedef unsigned long long u64;
typedef u64 u64x2 __attribute__((ext_vector_type(2)));

#define DIM 64
#define NSPLIT 12
#define USTRIDE 2048     // bytes per 32-col unit in Bp: 64 lanes x 32 B (lane-major)
#define MTILE 256        // rows per block (4 waves x 64 rows)

// ---- manual OCP e4m3fn encode (RNE, denormals, saturate) / decode ----
__device__ inline unsigned char enc_e4m3(float f) {
    unsigned int u = __float_as_uint(f);
    unsigned int s = (u >> 24) & 0x80u;
    unsigned int a = u & 0x7FFFFFFFu;
    if ((a >> 23) >= 121u) {                       // |f| >= 2^-6 : normal range
        unsigned int lsb = (a >> 20) & 1u;
        unsigned int r = a + 0x7FFFFu + lsb;       // RNE on 3-bit mantissa
        int e = (int)(r >> 23) - 120;              // rebias 127 -> 7
        unsigned int m = (r >> 20) & 7u;
        if (e > 15 || (e == 15 && m == 7u)) return (unsigned char)(s | 0x7Eu);  // sat 448
        return (unsigned char)(s | ((unsigned)e << 3) | m);
    }
    int m = (int)rintf(__uint_as_float(a) * 512.0f);   // denormal: multiples of 2^-9
    return (unsigned char)(s | (unsigned)m);
}

__device__ inline float dec_e4m3(unsigned char b) {
    int e = (b >> 3) & 15, m = b & 7;
    float v = (e == 0) ? (float)m * 0.001953125f       // 2^-9
                       : (float)(8 + m) * exp2f((float)(e - 10));
    return (b & 0x80) ? -v : v;
}

// ---------------- pack ----------------
// x -> Bp lane-major fp8: unit u = col>>5, half h, c31 = col&31:
//   Bp[u*2048 + (h*32 + c31)*32 + t*8 + j] = e4m3(x[col][t*16 + h*8 + j]),  t in [0,4)
// (so in igd_main, lane = h*32+c31 reads its unit's 32 B contiguously = 2x dwordx4)
// xsq[col] = exact fp32 sum of squares of decoded values.
// pf -> Ab row-major fp8(-2*pf); pfsq = 0.25 * sum(dec^2).
__global__ void pack_kernel(const float* __restrict__ x, const float* __restrict__ pf,
                            unsigned char* __restrict__ Bp, unsigned char* __restrict__ Ab,
                            float* __restrict__ xsq, float* __restrict__ pfsq,
                            float* __restrict__ out, int N, int M) {
    int gid = blockIdx.x * blockDim.x + threadIdx.x;
    if (gid == 0) out[0] = 0.f;
    if (gid < N * 4) {
        int col = gid >> 2, t = gid & 3;
        const float* s = x + (size_t)col * DIM + t * 16;
        float partial = 0.f;
        u64 w[2] = {0, 0};
#pragma unroll
        for (int h = 0; h < 2; ++h) {
            float4 v0 = *(const float4*)(s + h * 8);
            float4 v1 = *(const float4*)(s + h * 8 + 4);
            float f[8] = {v0.x, v0.y, v0.z, v0.w, v1.x, v1.y, v1.z, v1.w};
#pragma unroll
            for (int j = 0; j < 8; ++j) {
                unsigned char b = enc_e4m3(f[j]);
                w[h] |= (u64)b << (8 * j);
                float d = dec_e4m3(b);
                partial += d * d;
            }
        }
        int u = col >> 5, c31 = col & 31;
        unsigned char* ub = Bp + (size_t)u * USTRIDE;
        *(u64*)(ub + (size_t)c31 * 32 + t * 8)        = w[0];
        *(u64*)(ub + (size_t)(32 + c31) * 32 + t * 8) = w[1];
        partial += __shfl_xor(partial, 1);
        partial += __shfl_xor(partial, 2);
        if (t == 0) xsq[col] = partial;
    } else {
        int g = gid - N * 4;
        int row = g >> 2, q = g & 3;
        if (row >= M) return;
        const float* s = pf + (size_t)row * DIM + q * 16;
        float partial = 0.f;
        u64 w[2] = {0, 0};
#pragma unroll
        for (int h = 0; h < 2; ++h) {
            float4 v0 = *(const float4*)(s + h * 8);
            float4 v1 = *(const float4*)(s + h * 8 + 4);
            float f[8] = {v0.x, v0.y, v0.z, v0.w, v1.x, v1.y, v1.z, v1.w};
#pragma unroll
            for (int j = 0; j < 8; ++j) {
                unsigned char b = enc_e4m3(f[j] * -2.f);
                w[h] |= (u64)b << (8 * j);
                float d = dec_e4m3(b);
                partial += d * d;
            }
        }
        *(u64*)(Ab + (size_t)row * DIM + q * 16)     = w[0];
        *(u64*)(Ab + (size_t)row * DIM + q * 16 + 8) = w[1];
        partial += __shfl_xor(partial, 1);
        partial += __shfl_xor(partial, 2);
        if (q == 0) pfsq[row] = partial * 0.25f;
    }
}

// ---------------- main: fused fp8 GEMM + row-min, register-streamed B, depth-4 ----------------
__global__ __launch_bounds__(256, 3)
void igd_main(const unsigned char* __restrict__ A, const unsigned char* __restrict__ Bp,
              const float* __restrict__ xsq, float* __restrict__ partial, int N) {
    const int mTile  = blockIdx.x;
    const int nsplit = blockIdx.y;
    const int lane = threadIdx.x & 63;
    const int wave = threadIdx.x >> 6;
    const int half = lane >> 5;
    const int l31  = lane & 31;
    const int rowBase = mTile * MTILE + wave * 64;

    // ragged split over 32-col units: splits 0..7 get 43 units, 8..11 get 42
    const int utotal = N / 32;
    const int ubase  = utotal / NSPLIT;
    const int urem   = utotal % NSPLIT;
    const int ustart = nsplit * ubase + (nsplit < urem ? nsplit : urem);
    const int ucount = ubase + (nsplit < urem ? 1 : 0);

    // Persistent A fragments (fp8): lane holds A[row=l31+32g][k=half*8+j] per 16-k frag
    u64 a[2][4];
#pragma unroll
    for (int g = 0; g < 2; ++g) {
        const unsigned char* ap = A + (size_t)(rowBase + 32 * g + l31) * DIM + half * 8;
#pragma unroll
        for (int kf = 0; kf < 4; ++kf)
            a[g][kf] = *(const u64*)(ap + kf * 16);
    }

    f32x16 zero, m0, m1;
#pragma unroll
    for (int r = 0; r < 16; ++r) { zero[r] = 0.f; m0[r] = 1e30f; m1[r] = 1e30f; }

    const unsigned char* bbase = Bp + (size_t)ustart * USTRIDE + (size_t)lane * 32;
    const float* xbase = xsq + ustart * 32 + l31;

    u64x2 b0[2], b1[2], b2[2], b3[2];
    float xq0, xq1, xq2, xq3;

#define LOADU(breg, xq, u)                                                     \
    {                                                                          \
        const unsigned char* p = bbase + (size_t)(u) * USTRIDE;                \
        breg[0] = *(const u64x2*)(p);                                          \
        breg[1] = *(const u64x2*)(p + 16);                                     \
        xq = xbase[(u) * 32];                                                  \
    }

#define COMPUTE(breg, xq)                                                      \
    {                                                                          \
        f32x16 acc0 = __builtin_amdgcn_mfma_f32_32x32x16_fp8_fp8((long)a[0][0], (long)breg[0].x, zero, 0, 0, 0); \
        f32x16 acc1 = __builtin_amdgcn_mfma_f32_32x32x16_fp8_fp8((long)a[1][0], (long)breg[0].x, zero, 0, 0, 0); \
        acc0 = __builtin_amdgcn_mfma_f32_32x32x16_fp8_fp8((long)a[0][1], (long)breg[0].y, acc0, 0, 0, 0); \
        acc1 = __builtin_amdgcn_mfma_f32_32x32x16_fp8_fp8((long)a[1][1], (long)breg[0].y, acc1, 0, 0, 0); \
        acc0 = __builtin_amdgcn_mfma_f32_32x32x16_fp8_fp8((long)a[0][2], (long)breg[1].x, acc0, 0, 0, 0); \
        acc1 = __builtin_amdgcn_mfma_f32_32x32x16_fp8_fp8((long)a[1][2], (long)breg[1].x, acc1, 0, 0, 0); \
        acc0 = __builtin_amdgcn_mfma_f32_32x32x16_fp8_fp8((long)a[0][3], (long)breg[1].y, acc0, 0, 0, 0); \
        acc1 = __builtin_amdgcn_mfma_f32_32x32x16_fp8_fp8((long)a[1][3], (long)breg[1].y, acc1, 0, 0, 0); \
        _Pragma("unroll")                                                      \
        for (int r = 0; r < 16; ++r) {                                         \
            m0[r] = fminf(m0[r], acc0[r] + xq);                                \
            m1[r] = fminf(m1[r], acc1[r] + xq);                                \
        }                                                                      \
    }

    LOADU(b0, xq0, 0);
    LOADU(b1, xq1, 1);
    LOADU(b2, xq2, 2);
    LOADU(b3, xq3, 3);
    int u = 0;
    for (; u + 7 < ucount; u += 4) {
        COMPUTE(b0, xq0); LOADU(b0, xq0, u + 4);
        COMPUTE(b1, xq1); LOADU(b1, xq1, u + 5);
        COMPUTE(b2, xq2); LOADU(b2, xq2, u + 6);
        COMPUTE(b3, xq3); LOADU(b3, xq3, u + 7);
    }
    // tail: remaining = ucount - u in [4,7]
    COMPUTE(b0, xq0); if (u + 4 < ucount) LOADU(b0, xq0, u + 4);
    COMPUTE(b1, xq1); if (u + 5 < ucount) LOADU(b1, xq1, u + 5);
    COMPUTE(b2, xq2); if (u + 6 < ucount) LOADU(b2, xq2, u + 6);
    COMPUTE(b3, xq3);
    if (u + 4 < ucount) COMPUTE(b0, xq0);
    if (u + 5 < ucount) COMPUTE(b1, xq1);
    if (u + 6 < ucount) COMPUTE(b2, xq2);
#undef LOADU
#undef COMPUTE

    // cross-lane min over the 32 lanes sharing a row
#pragma unroll
    for (int mask = 1; mask <= 16; mask <<= 1) {
#pragma unroll
        for (int r = 0; r < 16; ++r) {
            m0[r] = fminf(m0[r], __shfl_xor(m0[r], mask));
            m1[r] = fminf(m1[r], __shfl_xor(m1[r], mask));
        }
    }
    if (l31 == 0) {
        // C/D layout (shape-determined): row = (r&3) + 8*(r>>2) + 4*half
#pragma unroll
        for (int r = 0; r < 16; ++r) {
            int row0 = rowBase + (r & 3) + 8 * (r >> 2) + 4 * half;
            partial[(size_t)row0 * NSPLIT + nsplit] = m0[r];
            partial[(size_t)(row0 + 32) * NSPLIT + nsplit] = m1[r];
        }
    }
}

// ---------------- reduce: min over splits, add pfsq, sqrt, mean ----------------
__global__ void reduce_kernel(const float* __restrict__ partial, const float* __restrict__ pfsq,
                              float* __restrict__ out, int M, float invM) {
    int row = blockIdx.x * blockDim.x + threadIdx.x;
    float v = 0.f;
    if (row < M) {
        const float* p = partial + (size_t)row * NSPLIT;
        float mn = 3.4e38f;
#pragma unroll
        for (int s = 0; s < NSPLIT; ++s) mn = fminf(mn, p[s]);
        float d2 = mn + pfsq[row];
        v = sqrtf(fmaxf(d2, 0.f)) * invM;
    }
#pragma unroll
    for (int m = 1; m < 64; m <<= 1) v += __shfl_xor(v, m);
    __shared__ float wsum[4];
    int lane = threadIdx.x & 63, w = threadIdx.x >> 6;
    if (lane == 0) wsum[w] = v;
    __syncthreads();
    if (threadIdx.x == 0) atomicAdd(out, wsum[0] + wsum[1] + wsum[2] + wsum[3]);
}

extern "C" void kernel_launch(void* const* d_in, const int* in_sizes, int n_in,
                              void* d_out, int out_size, void* d_ws, size_t ws_size,
                              hipStream_t stream) {
    const float* x  = (const float*)d_in[0];   // [N, 64]
    const float* pf = (const float*)d_in[1];   // [M, 64]
    const int N = in_sizes[0] / DIM;
    const int M = in_sizes[1] / DIM;

    char* ws = (char*)d_ws;
    unsigned char* Bp = (unsigned char*)ws;                        // N*64 bytes (packed fp8)
    unsigned char* Ab = (unsigned char*)(ws + (size_t)N * DIM);    // M*64 bytes
    float* xsq  = (float*)(ws + (size_t)(N + M) * DIM);            // N floats
    float* pfsq = xsq + N;                                         // M floats
    float* part = pfsq + M;                                        // M*NSPLIT floats

    int packThreads = (N + M) * 4;
    pack_kernel<<<dim3((packThreads + 255) / 256), 256, 0, stream>>>(
        x, pf, Bp, Ab, xsq, pfsq, (float*)d_out, N, M);
    igd_main<<<dim3(M / MTILE, NSPLIT), 256, 0, stream>>>(Ab, Bp, xsq, part, N);
    reduce_kernel<<<dim3((M + 255) / 256), 256, 0, stream>>>(part, pfsq, (float*)d_out, M, 1.f / (float)M);
}

// Round 7
// 97.384 us; speedup vs baseline: 1.3051x; 1.0112x over previous
//
#include <hip/hip_runtime.h>

// IGD metric kernel for MI355X (gfx950) — R7: fp8 e4m3, block-cooperative LDS double-buffer.
// d2(i,j) = pfsq[i] + xsq[j] + dot(e4m3(-2*pf_i), e4m3(x_j)); norms in fp32 from DECODED fp8 ->
// d2 = exact sq-distance between rounded points; only point-rounding (~0.02/dist) reaches output.
// R6 post-mortem: register-level prefetch collapsed by regalloc (VGPR=84 -> loads sunk to uses,
// depth ~1) + 4x per-wave VMEM redundancy -> ~2300 cyc/unit latency-bound. R7: each block stages
// 8-unit (16 KB) chunks into a 2x16KB LDS double buffer cooperatively (one barrier/chunk, loads
// issued a full chunk of compute ahead); K-loop reads fragments via ds_read_b64 stride-8
// (2-way bank alias = free, 0 conflicts in R5). Grid stays 768 = exactly 3 blocks/CU, one round.
// Harness poison fill of ws (~42 us @6.4TB/s) is a fixed floor inside the timed window.

typedef float f32x16 __attribute__((ext_vector_type(16)));
typedef unsigned long long u64;

#define DIM 64
#define NSPLIT 12
#define UNITB 2048            // bytes per 32-col unit (fragment-linear: 4 frags x 64 lanes x 8 B)
#define CHUNKU 8              // units per LDS chunk
#define CHUNKB (CHUNKU * UNITB)   // 16 KB
#define MTILE 256             // rows per block (4 waves x 64 rows)

// ---- manual OCP e4m3fn encode (RNE, denormals, saturate) / decode (bit-exact, cheap) ----
__device__ inline unsigned char enc_e4m3(float f) {
    unsigned int u = __float_as_uint(f);
    unsigned int s = (u >> 24) & 0x80u;
    unsigned int a = u & 0x7FFFFFFFu;
    if ((a >> 23) >= 121u) {                       // |f| >= 2^-6 : normal range
        unsigned int lsb = (a >> 20) & 1u;
        unsigned int r = a + 0x7FFFFu + lsb;       // RNE on 3-bit mantissa
        int e = (int)(r >> 23) - 120;              // rebias 127 -> 7
        unsigned int m = (r >> 20) & 7u;
        if (e > 15 || (e == 15 && m == 7u)) return (unsigned char)(s | 0x7Eu);  // sat 448
        return (unsigned char)(s | ((unsigned)e << 3) | m);
    }
    int m = (int)rintf(__uint_as_float(a) * 512.0f);   // denormal: multiples of 2^-9
    return (unsigned char)(s | (unsigned)m);
}

__device__ inline float dec_e4m3(unsigned char b) {
    int e = (b >> 3) & 15, m = b & 7;
    float v = e ? __uint_as_float((unsigned)((e + 120) << 23) | ((unsigned)m << 20))
                : (float)m * 0.001953125f;         // 2^-9
    return (b & 0x80) ? -v : v;
}

// ---------------- pack ----------------
// x -> Bp fragment-linear fp8: unit u = col>>5, frag t, c31 = col&31:
//   Bp[u*2048 + t*512 + c31*8 + j]      = e4m3(x[col][t*16 + j])       (half 0)
//   Bp[u*2048 + t*512 + (32+c31)*8 + j] = e4m3(x[col][t*16 + 8 + j])   (half 1)
// xsq[col] = exact fp32 sum of squares of decoded values.
// pf -> Ab row-major fp8(-2*pf); pfsq = 0.25 * sum(dec^2).
__global__ void pack_kernel(const float* __restrict__ x, const float* __restrict__ pf,
                            unsigned char* __restrict__ Bp, unsigned char* __restrict__ Ab,
                            float* __restrict__ xsq, float* __restrict__ pfsq,
                            float* __restrict__ out, int N, int M) {
    int gid = blockIdx.x * blockDim.x + threadIdx.x;
    if (gid == 0) out[0] = 0.f;
    if (gid < N * 4) {
        int col = gid >> 2, t = gid & 3;
        const float* s = x + (size_t)col * DIM + t * 16;
        float partial = 0.f;
        u64 w[2] = {0, 0};
#pragma unroll
        for (int h = 0; h < 2; ++h) {
            float4 v0 = *(const float4*)(s + h * 8);
            float4 v1 = *(const float4*)(s + h * 8 + 4);
            float f[8] = {v0.x, v0.y, v0.z, v0.w, v1.x, v1.y, v1.z, v1.w};
#pragma unroll
            for (int j = 0; j < 8; ++j) {
                unsigned char b = enc_e4m3(f[j]);
                w[h] |= (u64)b << (8 * j);
                float d = dec_e4m3(b);
                partial += d * d;
            }
        }
        int u = col >> 5, c31 = col & 31;
        unsigned char* ub = Bp + (size_t)u * UNITB + (size_t)t * 512;
        *(u64*)(ub + (size_t)c31 * 8)        = w[0];
        *(u64*)(ub + (size_t)(32 + c31) * 8) = w[1];
        partial += __shfl_xor(partial, 1);
        partial += __shfl_xor(partial, 2);
        if (t == 0) xsq[col] = partial;
    } else {
        int g = gid - N * 4;
        int row = g >> 2, q = g & 3;
        if (row >= M) return;
        const float* s = pf + (size_t)row * DIM + q * 16;
        float partial = 0.f;
        u64 w[2] = {0, 0};
#pragma unroll
        for (int h = 0; h < 2; ++h) {
            float4 v0 = *(const float4*)(s + h * 8);
            float4 v1 = *(const float4*)(s + h * 8 + 4);
            float f[8] = {v0.x, v0.y, v0.z, v0.w, v1.x, v1.y, v1.z, v1.w};
#pragma unroll
            for (int j = 0; j < 8; ++j) {
                unsigned char b = enc_e4m3(f[j] * -2.f);
                w[h] |= (u64)b << (8 * j);
                float d = dec_e4m3(b);
                partial += d * d;
            }
        }
        *(u64*)(Ab + (size_t)row * DIM + q * 16)     = w[0];
        *(u64*)(Ab + (size_t)row * DIM + q * 16 + 8) = w[1];
        partial += __shfl_xor(partial, 1);
        partial += __shfl_xor(partial, 2);
        if (q == 0) pfsq[row] = partial * 0.25f;
    }
}

// ---------------- main: LDS double-buffered fp8 GEMM + row-min ----------------
__global__ __launch_bounds__(256, 3)
void igd_main(const unsigned char* __restrict__ A, const unsigned char* __restrict__ Bp,
              const float* __restrict__ xsq, float* __restrict__ partial, int N) {
    __shared__ unsigned char ldsB[2][CHUNKB];     // 32 KB
    __shared__ float ldsX[2][CHUNKU * 32];        // 2 KB
    const int tid = threadIdx.x;
    const int mTile  = blockIdx.x;
    const int nsplit = blockIdx.y;
    const int lane = tid & 63;
    const int wave = tid >> 6;
    const int half = lane >> 5;
    const int l31  = lane & 31;
    const int rowBase = mTile * MTILE + wave * 64;

    // ragged split over 32-col units: splits 0..7 get 43, 8..11 get 42
    const int utotal = N / 32;
    const int ubase  = utotal / NSPLIT;
    const int urem   = utotal % NSPLIT;
    const int ustart = nsplit * ubase + (nsplit < urem ? nsplit : urem);
    const int ucount = ubase + (nsplit < urem ? 1 : 0);
    const int nch = (ucount + CHUNKU - 1) / CHUNKU;

    // Persistent A fragments (fp8): lane holds A[row=l31+32g][k=half*8+j] per 16-k frag
    u64 a[2][4];
#pragma unroll
    for (int g = 0; g < 2; ++g) {
        const unsigned char* ap = A + (size_t)(rowBase + 32 * g + l31) * DIM + half * 8;
#pragma unroll
        for (int kf = 0; kf < 4; ++kf)
            a[g][kf] = *(const u64*)(ap + kf * 16);
    }

    const unsigned char* gB = Bp + (size_t)ustart * UNITB;
    const float* gX = xsq + ustart * 32;

    // cooperative stage of chunk c into buffer buf: lane-stride-16B (2 lanes/bank = free)
#define STAGE(c, buf)                                                          \
    {                                                                          \
        int bytes = (ucount - (c) * CHUNKU) < CHUNKU ? (ucount - (c) * CHUNKU) * UNITB : CHUNKB; \
        const unsigned char* src = gB + (size_t)(c) * CHUNKB;                  \
        _Pragma("unroll")                                                      \
        for (int i = 0; i < 4; ++i) {                                          \
            int off = i * 4096 + tid * 16;                                     \
            if (off < bytes)                                                   \
                *(float4*)(&ldsB[buf][off]) = *(const float4*)(src + off);     \
        }                                                                      \
        int xcnt = bytes >> 6;                                                 \
        if (tid < xcnt) ldsX[buf][tid] = gX[(c) * (CHUNKU * 32) + tid];        \
    }

    f32x16 zero, m0, m1;
#pragma unroll
    for (int r = 0; r < 16; ++r) { zero[r] = 0.f; m0[r] = 1e30f; m1[r] = 1e30f; }

    u64 r0[4], r1[4];

#define LOADF(rr, lb, u)                                                       \
    {                                                                          \
        const unsigned char* p = (lb) + (u) * UNITB;                           \
        rr[0] = *(const u64*)(p);                                              \
        rr[1] = *(const u64*)(p + 512);                                        \
        rr[2] = *(const u64*)(p + 1024);                                       \
        rr[3] = *(const u64*)(p + 1536);                                       \
    }

#define COMPUTE(rr, xq)                                                        \
    {                                                                          \
        f32x16 acc0 = __builtin_amdgcn_mfma_f32_32x32x16_fp8_fp8((long)a[0][0], (long)rr[0], zero, 0, 0, 0); \
        f32x16 acc1 = __builtin_amdgcn_mfma_f32_32x32x16_fp8_fp8((long)a[1][0], (long)rr[0], zero, 0, 0, 0); \
        acc0 = __builtin_amdgcn_mfma_f32_32x32x16_fp8_fp8((long)a[0][1], (long)rr[1], acc0, 0, 0, 0); \
        acc1 = __builtin_amdgcn_mfma_f32_32x32x16_fp8_fp8((long)a[1][1], (long)rr[1], acc1, 0, 0, 0); \
        acc0 = __builtin_amdgcn_mfma_f32_32x32x16_fp8_fp8((long)a[0][2], (long)rr[2], acc0, 0, 0, 0); \
        acc1 = __builtin_amdgcn_mfma_f32_32x32x16_fp8_fp8((long)a[1][2], (long)rr[2], acc1, 0, 0, 0); \
        acc0 = __builtin_amdgcn_mfma_f32_32x32x16_fp8_fp8((long)a[0][3], (long)rr[3], acc0, 0, 0, 0); \
        acc1 = __builtin_amdgcn_mfma_f32_32x32x16_fp8_fp8((long)a[1][3], (long)rr[3], acc1, 0, 0, 0); \
        _Pragma("unroll")                                                      \
        for (int r = 0; r < 16; ++r) {                                         \
            m0[r] = fminf(m0[r], acc0[r] + (xq));                              \
            m1[r] = fminf(m1[r], acc1[r] + (xq));                              \
        }                                                                      \
    }

    STAGE(0, 0);
    __syncthreads();

    for (int c = 0; c < nch; ++c) {
        const int buf = c & 1;
        if (c + 1 < nch) STAGE(c + 1, buf ^ 1);          // issued a full chunk of compute early
        const int cnt = (ucount - c * CHUNKU) < CHUNKU ? (ucount - c * CHUNKU) : CHUNKU;
        const unsigned char* lb = &ldsB[buf][0] + lane * 8;
        const float* lx = &ldsX[buf][0] + l31;
        if (cnt == CHUNKU) {
            LOADF(r0, lb, 0);
#pragma unroll
            for (int u = 0; u < CHUNKU; u += 2) {
                LOADF(r1, lb, u + 1);
                COMPUTE(r0, lx[u * 32]);
                if (u + 2 < CHUNKU) LOADF(r0, lb, u + 2);
                COMPUTE(r1, lx[(u + 1) * 32]);
            }
        } else {
            for (int u = 0; u < cnt; ++u) {              // tail chunk: 2 or 3 units
                LOADF(r0, lb, u);
                COMPUTE(r0, lx[u * 32]);
            }
        }
        __syncthreads();
    }
#undef STAGE
#undef LOADF
#undef COMPUTE

    // cross-lane min over the 32 lanes sharing a row
#pragma unroll
    for (int mask = 1; mask <= 16; mask <<= 1) {
#pragma unroll
        for (int r = 0; r < 16; ++r) {
            m0[r] = fminf(m0[r], __shfl_xor(m0[r], mask));
            m1[r] = fminf(m1[r], __shfl_xor(m1[r], mask));
        }
    }
    if (l31 == 0) {
        // C/D layout (shape-determined): row = (r&3) + 8*(r>>2) + 4*half
#pragma unroll
        for (int r = 0; r < 16; ++r) {
            int row0 = rowBase + (r & 3) + 8 * (r >> 2) + 4 * half;
            partial[(size_t)row0 * NSPLIT + nsplit] = m0[r];
            partial[(size_t)(row0 + 32) * NSPLIT + nsplit] = m1[r];
        }
    }
}

// ---------------- reduce: min over splits, add pfsq, sqrt, mean ----------------
__global__ void reduce_kernel(const float* __restrict__ partial, const float* __restrict__ pfsq,
                              float* __restrict__ out, int M, float invM) {
    int row = blockIdx.x * blockDim.x + threadIdx.x;
    float v = 0.f;
    if (row < M) {
        const float* p = partial + (size_t)row * NSPLIT;
        float mn = 3.4e38f;
#pragma unroll
        for (int s = 0; s < NSPLIT; ++s) mn = fminf(mn, p[s]);
        float d2 = mn + pfsq[row];
        v = sqrtf(fmaxf(d2, 0.f)) * invM;
    }
#pragma unroll
    for (int m = 1; m < 64; m <<= 1) v += __shfl_xor(v, m);
    __shared__ float wsum[4];
    int lane = threadIdx.x & 63, w = threadIdx.x >> 6;
    if (lane == 0) wsum[w] = v;
    __syncthreads();
    if (threadIdx.x == 0) atomicAdd(out, wsum[0] + wsum[1] + wsum[2] + wsum[3]);
}

extern "C" void kernel_launch(void* const* d_in, const int* in_sizes, int n_in,
                              void* d_out, int out_size, void* d_ws, size_t ws_size,
                              hipStream_t stream) {
    const float* x  = (const float*)d_in[0];   // [N, 64]
    const float* pf = (const float*)d_in[1];   // [M, 64]
    const int N = in_sizes[0] / DIM;
    const int M = in_sizes[1] / DIM;

    char* ws = (char*)d_ws;
    unsigned char* Bp = (unsigned char*)ws;                        // N*64 bytes (packed fp8)
    unsigned char* Ab = (unsigned char*)(ws + (size_t)N * DIM);    // M*64 bytes
    float* xsq  = (float*)(ws + (size_t)(N + M) * DIM);            // N floats
    float* pfsq = xsq + N;                                         // M floats
    float* part = pfsq + M;                                        // M*NSPLIT floats

    int packThreads = (N + M) * 4;
    pack_kernel<<<dim3((packThreads + 255) / 256), 256, 0, stream>>>(
        x, pf, Bp, Ab, xsq, pfsq, (float*)d_out, N, M);
    igd_main<<<dim3(M / MTILE, NSPLIT), 256, 0, stream>>>(Ab, Bp, xsq, part, N);
    reduce_kernel<<<dim3((M + 255) / 256), 256, 0, stream>>>(part, pfsq, (float*)d_out, M, 1.f / (float)M);
}

// Round 8
// 92.312 us; speedup vs baseline: 1.3768x; 1.0549x over previous
//
#include <hip/hip_runtime.h>

// IGD metric kernel for MI355X (gfx950) — R8: MX-scaled fp8 MFMA (K=64/instr, unity scales).
// d2(i,j) = pfsq[i] + xsq[j] + dot(e4m3(-2*pf_i), e4m3(x_j)); norms in fp32 from DECODED fp8 ->
// d2 = exact sq-distance between rounded points (scale=2^0 makes scaled MFMA bit-identical to
// the non-scaled fp8 chain). R3-R7 post-mortem: throughput pinned at ~777 SIMD-cyc/wave-unit =
// 3x the MFMA-pipe demand across ALL delivery structures -> dependent 4-deep acc chains leave
// the matrix pipe idle. R8: v_mfma_scale_f32_32x32x64_f8f6f4 does K=64 in ONE instruction:
// 2 unchained MFMAs/unit (was 8 chained), floor 13.8 -> 7.3 us (MX rate 4686 TF, m59).
// Delivery kept from R7: cooperative 16KB LDS double-buffer, stride-8 frag reads (0 conflicts).
// Harness poison fill of ws (~42 us @6.4TB/s) is a fixed floor inside the timed window.

typedef float f32x16 __attribute__((ext_vector_type(16)));
typedef int i32x8 __attribute__((ext_vector_type(8)));
typedef unsigned long long u64;

#define DIM 64
#define NSPLIT 12
#define UNITB 2048            // bytes per 32-col unit: 4 qfrags x 64 lanes x 8 B
#define CHUNKU 8              // units per LDS chunk
#define CHUNKB (CHUNKU * UNITB)   // 16 KB
#define MTILE 256             // rows per block (4 waves x 64 rows)

union BFrag { u64 q[4]; i32x8 v; };

// ---- manual OCP e4m3fn encode (RNE, denormals, saturate) / decode ----
__device__ inline unsigned char enc_e4m3(float f) {
    unsigned int u = __float_as_uint(f);
    unsigned int s = (u >> 24) & 0x80u;
    unsigned int a = u & 0x7FFFFFFFu;
    if ((a >> 23) >= 121u) {                       // |f| >= 2^-6 : normal range
        unsigned int lsb = (a >> 20) & 1u;
        unsigned int r = a + 0x7FFFFu + lsb;       // RNE on 3-bit mantissa
        int e = (int)(r >> 23) - 120;              // rebias 127 -> 7
        unsigned int m = (r >> 20) & 7u;
        if (e > 15 || (e == 15 && m == 7u)) return (unsigned char)(s | 0x7Eu);  // sat 448
        return (unsigned char)(s | ((unsigned)e << 3) | m);
    }
    int m = (int)rintf(__uint_as_float(a) * 512.0f);   // denormal: multiples of 2^-9
    return (unsigned char)(s | (unsigned)m);
}

__device__ inline float dec_e4m3(unsigned char b) {
    int e = (b >> 3) & 15, m = b & 7;
    float v = e ? __uint_as_float((unsigned)((e + 120) << 23) | ((unsigned)m << 20))
                : (float)m * 0.001953125f;         // 2^-9
    return (b & 0x80) ? -v : v;
}

// ---------------- pack ----------------
// Bp layout for the 32x32x64 B-operand: lane L = h*32 + c31 holds col = u*32+c31,
// k = h*32 + 0..31 as 4 qwords: Bp[u*2048 + q*512 + L*8 + b] = e4m3(x[col][h*32 + q*8 + b]).
// Thread (col, t) covers k = t*16..t*16+15: h = t>>1, q = (t&1)*2 + s for s in {0,1}.
// xsq[col] = exact fp32 sum of squares of decoded values.
// pf -> Ab row-major fp8(-2*pf) (A-operand = contiguous 32 B per lane); pfsq = 0.25*sum(dec^2).
__global__ void pack_kernel(const float* __restrict__ x, const float* __restrict__ pf,
                            unsigned char* __restrict__ Bp, unsigned char* __restrict__ Ab,
                            float* __restrict__ xsq, float* __restrict__ pfsq,
                            float* __restrict__ out, int N, int M) {
    int gid = blockIdx.x * blockDim.x + threadIdx.x;
    if (gid == 0) out[0] = 0.f;
    if (gid < N * 4) {
        int col = gid >> 2, t = gid & 3;
        const float* s = x + (size_t)col * DIM + t * 16;
        float partial = 0.f;
        u64 w[2] = {0, 0};
#pragma unroll
        for (int h = 0; h < 2; ++h) {
            float4 v0 = *(const float4*)(s + h * 8);
            float4 v1 = *(const float4*)(s + h * 8 + 4);
            float f[8] = {v0.x, v0.y, v0.z, v0.w, v1.x, v1.y, v1.z, v1.w};
#pragma unroll
            for (int j = 0; j < 8; ++j) {
                unsigned char b = enc_e4m3(f[j]);
                w[h] |= (u64)b << (8 * j);
                float d = dec_e4m3(b);
                partial += d * d;
            }
        }
        int u = col >> 5, c31 = col & 31;
        unsigned char* ub = Bp + (size_t)u * UNITB;
        int h = t >> 1;
#pragma unroll
        for (int ss = 0; ss < 2; ++ss) {
            int q = (t & 1) * 2 + ss;
            *(u64*)(ub + (size_t)q * 512 + (size_t)(h * 32 + c31) * 8) = w[ss];
        }
        partial += __shfl_xor(partial, 1);
        partial += __shfl_xor(partial, 2);
        if (t == 0) xsq[col] = partial;
    } else {
        int g = gid - N * 4;
        int row = g >> 2, q = g & 3;
        if (row >= M) return;
        const float* s = pf + (size_t)row * DIM + q * 16;
        float partial = 0.f;
        u64 w[2] = {0, 0};
#pragma unroll
        for (int h = 0; h < 2; ++h) {
            float4 v0 = *(const float4*)(s + h * 8);
            float4 v1 = *(const float4*)(s + h * 8 + 4);
            float f[8] = {v0.x, v0.y, v0.z, v0.w, v1.x, v1.y, v1.z, v1.w};
#pragma unroll
            for (int j = 0; j < 8; ++j) {
                unsigned char b = enc_e4m3(f[j] * -2.f);
                w[h] |= (u64)b << (8 * j);
                float d = dec_e4m3(b);
                partial += d * d;
            }
        }
        *(u64*)(Ab + (size_t)row * DIM + q * 16)     = w[0];
        *(u64*)(Ab + (size_t)row * DIM + q * 16 + 8) = w[1];
        partial += __shfl_xor(partial, 1);
        partial += __shfl_xor(partial, 2);
        if (q == 0) pfsq[row] = partial * 0.25f;
    }
}

// ---------------- main: LDS double-buffered, K=64-per-instruction fp8 GEMM + row-min ----------
__global__ __launch_bounds__(256, 3)
void igd_main(const unsigned char* __restrict__ A, const unsigned char* __restrict__ Bp,
              const float* __restrict__ xsq, float* __restrict__ partial, int N) {
    __shared__ unsigned char ldsB[2][CHUNKB];     // 32 KB
    __shared__ float ldsX[2][CHUNKU * 32];        // 2 KB
    const int tid = threadIdx.x;
    const int mTile  = blockIdx.x;
    const int nsplit = blockIdx.y;
    const int lane = tid & 63;
    const int wave = tid >> 6;
    const int half = lane >> 5;
    const int l31  = lane & 31;
    const int rowBase = mTile * MTILE + wave * 64;

    // ragged split over 32-col units: splits 0..7 get 43, 8..11 get 42
    const int utotal = N / 32;
    const int ubase  = utotal / NSPLIT;
    const int urem   = utotal % NSPLIT;
    const int ustart = nsplit * ubase + (nsplit < urem ? nsplit : urem);
    const int ucount = ubase + (nsplit < urem ? 1 : 0);
    const int nch = (ucount + CHUNKU - 1) / CHUNKU;

    // Persistent A operands: lane holds A[row = l31 + 32g][k = half*32 .. +31] (32 B contiguous)
    BFrag a[2];
#pragma unroll
    for (int g = 0; g < 2; ++g) {
        const unsigned char* ap = A + (size_t)(rowBase + 32 * g + l31) * DIM + half * 32;
#pragma unroll
        for (int qq = 0; qq < 4; ++qq)
            a[g].q[qq] = *(const u64*)(ap + qq * 8);
    }

    const unsigned char* gB = Bp + (size_t)ustart * UNITB;
    const float* gX = xsq + ustart * 32;

#define STAGE(c, buf)                                                          \
    {                                                                          \
        int bytes = (ucount - (c) * CHUNKU) < CHUNKU ? (ucount - (c) * CHUNKU) * UNITB : CHUNKB; \
        const unsigned char* src = gB + (size_t)(c) * CHUNKB;                  \
        _Pragma("unroll")                                                      \
        for (int i = 0; i < 4; ++i) {                                          \
            int off = i * 4096 + tid * 16;                                     \
            if (off < bytes)                                                   \
                *(float4*)(&ldsB[buf][off]) = *(const float4*)(src + off);     \
        }                                                                      \
        int xcnt = bytes >> 6;                                                 \
        if (tid < xcnt) ldsX[buf][tid] = gX[(c) * (CHUNKU * 32) + tid];        \
    }

    f32x16 zero, m0, m1;
#pragma unroll
    for (int r = 0; r < 16; ++r) { zero[r] = 0.f; m0[r] = 1e30f; m1[r] = 1e30f; }

    BFrag b0, b1;

#define LOADF(rr, lb, u)                                                       \
    {                                                                          \
        const unsigned char* p = (lb) + (u) * UNITB;                           \
        rr.q[0] = *(const u64*)(p);                                            \
        rr.q[1] = *(const u64*)(p + 512);                                      \
        rr.q[2] = *(const u64*)(p + 1024);                                     \
        rr.q[3] = *(const u64*)(p + 1536);                                     \
    }

    // Unity E8M0 scales (0x7F = 2^0): bit-identical to non-scaled fp8 accumulation.
#define COMPUTE(rr, xq)                                                        \
    {                                                                          \
        f32x16 acc0 = __builtin_amdgcn_mfma_scale_f32_32x32x64_f8f6f4(         \
            a[0].v, rr.v, zero, 0, 0, 0, 0x7F7F7F7F, 0, 0x7F7F7F7F);           \
        f32x16 acc1 = __builtin_amdgcn_mfma_scale_f32_32x32x64_f8f6f4(         \
            a[1].v, rr.v, zero, 0, 0, 0, 0x7F7F7F7F, 0, 0x7F7F7F7F);           \
        _Pragma("unroll")                                                      \
        for (int r = 0; r < 16; ++r) {                                         \
            m0[r] = fminf(m0[r], acc0[r] + (xq));                              \
            m1[r] = fminf(m1[r], acc1[r] + (xq));                              \
        }                                                                      \
    }

    STAGE(0, 0);
    __syncthreads();

    for (int c = 0; c < nch; ++c) {
        const int buf = c & 1;
        if (c + 1 < nch) STAGE(c + 1, buf ^ 1);
        const int cnt = (ucount - c * CHUNKU) < CHUNKU ? (ucount - c * CHUNKU) : CHUNKU;
        const unsigned char* lb = &ldsB[buf][0] + lane * 8;
        const float* lx = &ldsX[buf][0] + l31;
        if (cnt == CHUNKU) {
            LOADF(b0, lb, 0);
#pragma unroll
            for (int u = 0; u < CHUNKU; u += 2) {
                LOADF(b1, lb, u + 1);
                COMPUTE(b0, lx[u * 32]);
                if (u + 2 < CHUNKU) LOADF(b0, lb, u + 2);
                COMPUTE(b1, lx[(u + 1) * 32]);
            }
        } else {
            for (int u = 0; u < cnt; ++u) {              // tail chunk: 2 or 3 units
                LOADF(b0, lb, u);
                COMPUTE(b0, lx[u * 32]);
            }
        }
        __syncthreads();
    }
#undef STAGE
#undef LOADF
#undef COMPUTE

    // cross-lane min over the 32 lanes sharing a row
#pragma unroll
    for (int mask = 1; mask <= 16; mask <<= 1) {
#pragma unroll
        for (int r = 0; r < 16; ++r) {
            m0[r] = fminf(m0[r], __shfl_xor(m0[r], mask));
            m1[r] = fminf(m1[r], __shfl_xor(m1[r], mask));
        }
    }
    if (l31 == 0) {
        // C/D layout (shape-determined, FMT-independent — m128): row = (r&3)+8*(r>>2)+4*half
#pragma unroll
        for (int r = 0; r < 16; ++r) {
            int row0 = rowBase + (r & 3) + 8 * (r >> 2) + 4 * half;
            partial[(size_t)row0 * NSPLIT + nsplit] = m0[r];
            partial[(size_t)(row0 + 32) * NSPLIT + nsplit] = m1[r];
        }
    }
}

// ---------------- reduce: min over splits, add pfsq, sqrt, mean ----------------
__global__ void reduce_kernel(const float* __restrict__ partial, const float* __restrict__ pfsq,
                              float* __restrict__ out, int M, float invM) {
    int row = blockIdx.x * blockDim.x + threadIdx.x;
    float v = 0.f;
    if (row < M) {
        const float* p = partial + (size_t)row * NSPLIT;
        float mn = 3.4e38f;
#pragma unroll
        for (int s = 0; s < NSPLIT; ++s) mn = fminf(mn, p[s]);
        float d2 = mn + pfsq[row];
        v = sqrtf(fmaxf(d2, 0.f)) * invM;
    }
#pragma unroll
    for (int m = 1; m < 64; m <<= 1) v += __shfl_xor(v, m);
    __shared__ float wsum[4];
    int lane = threadIdx.x & 63, w = threadIdx.x >> 6;
    if (lane == 0) wsum[w] = v;
    __syncthreads();
    if (threadIdx.x == 0) atomicAdd(out, wsum[0] + wsum[1] + wsum[2] + wsum[3]);
}

extern "C" void kernel_launch(void* const* d_in, const int* in_sizes, int n_in,
                              void* d_out, int out_size, void* d_ws, size_t ws_size,
                              hipStream_t stream) {
    const float* x  = (const float*)d_in[0];   // [N, 64]
    const float* pf = (const float*)d_in[1];   // [M, 64]
    const int N = in_sizes[0] / DIM;
    const int M = in_sizes[1] / DIM;

    char* ws = (char*)d_ws;
    unsigned char* Bp = (unsigned char*)ws;                        // N*64 bytes (packed fp8)
    unsigned char* Ab = (unsigned char*)(ws + (size_t)N * DIM);    // M*64 bytes
    float* xsq  = (float*)(ws + (size_t)(N + M) * DIM);            // N floats
    float* pfsq = xsq + N;                                         // M floats
    float* part = pfsq + M;                                        // M*NSPLIT floats

    int packThreads = (N + M) * 4;
    pack_kernel<<<dim3((packThreads + 255) / 256), 256, 0, stream>>>(
        x, pf, Bp, Ab, xsq, pfsq, (float*)d_out, N, M);
    igd_main<<<dim3(M / MTILE, NSPLIT), 256, 0, stream>>>(Ab, Bp, xsq, part, N);
    reduce_kernel<<<dim3((M + 255) / 256), 256, 0, stream>>>(part, pfsq, (float*)d_out, M, 1.f / (float)M);
}